// Round 1
// 1342.210 us; speedup vs baseline: 1.5736x; 1.5736x over previous
//
#include <hip/hip_runtime.h>

#define E_N   10000
#define SB_N  49
#define SBR_N 19
#define C_N   128
#define H_N   256
#define NBF_N 512
#define KPROJ 4864   // 2*SBR*C
#define NOUT  2432   // SBR*C

typedef _Float16 f16x8 __attribute__((ext_vector_type(8)));
typedef _Float16 f16x4 __attribute__((ext_vector_type(4)));
typedef float    f32x4 __attribute__((ext_vector_type(4)));

__device__ __forceinline__ float silu_f(float v) { return v / (1.0f + __expf(-v)); }

#define GLOBAL_PTR(p) ((const __attribute__((address_space(1))) void*)(p))
#define LDS_PTR(p)    ((__attribute__((address_space(3))) void*)(p))

// ---------------------------------------------------------------------------
// Tiled transpose + fp32->fp16: out[n*K + k] = (f16) in[k*N + n]
// grid: (ceil(K/32), ceil(N/32)), 256 threads (32x8)
// ---------------------------------------------------------------------------
__launch_bounds__(256)
__global__ void transpose_to_f16(const float* __restrict__ in, _Float16* __restrict__ out,
                                 int K, int N)
{
    __shared__ float tile[32][33];
    const int k0 = blockIdx.x * 32;
    const int n0 = blockIdx.y * 32;
    const int tx = threadIdx.x & 31;
    const int ty = threadIdx.x >> 5;           // 0..7
    #pragma unroll
    for (int i = ty; i < 32; i += 8)
        if (k0 + i < K && n0 + tx < N)
            tile[i][tx] = in[(size_t)(k0 + i) * N + (n0 + tx)];
    __syncthreads();
    #pragma unroll
    for (int i = ty; i < 32; i += 8)
        if (n0 + i < N && k0 + tx < K)
            out[(size_t)(n0 + i) * K + (k0 + tx)] = (_Float16)tile[tx][i];
}

// ---------------------------------------------------------------------------
// fp32 -> fp16 bulk convert (float4 -> 4x f16), n4 = n/4
// ---------------------------------------------------------------------------
__launch_bounds__(256)
__global__ void cvt_to_f16(const float* __restrict__ in, _Float16* __restrict__ out, int n4)
{
    int i = blockIdx.x * blockDim.x + threadIdx.x;
    const int stride = gridDim.x * blockDim.x;
    for (; i < n4; i += stride) {
        const float4 v = ((const float4*)in)[i];
        f16x4 o; o[0] = (_Float16)v.x; o[1] = (_Float16)v.y; o[2] = (_Float16)v.z; o[3] = (_Float16)v.w;
        ((f16x4*)out)[i] = o;
    }
}

// ---------------------------------------------------------------------------
// MFMA GEMM: C[M,N](f16) = silu(A[M,K](f16) @ BT[N,K](f16)^T + bias[N]) [* gate]
// BM=BN=128, BK=32, 256 threads = 4 waves (2x2), 4x4 16x16x32 frags per wave.
// LDS layout k-sliced: As[kslot][row][8] so frag ds_read_b128 is conflict-free,
// and global_load_lds (wave-uniform base + lane*16) fills it linearly.
// A must be allocated with ceil(M/128)*128 rows (pad rows read, results masked).
// Requires K%32==0, N%128==0.
// grid: (N/128, ceil(M/128)) -- N fastest so N-blocks reuse the A panel in L2.
// ---------------------------------------------------------------------------
template<int GATED>
__launch_bounds__(256, 2)
__global__ void gemm_f16(const _Float16* __restrict__ A, int lda,
                         const _Float16* __restrict__ BT,
                         const float* __restrict__ bias,
                         const _Float16* __restrict__ gate,
                         _Float16* __restrict__ C,
                         int M, int N, int K, int i0)
{
    __shared__ __align__(16) _Float16 As[4][128][8];
    __shared__ __align__(16) _Float16 Bs[4][128][8];
    const int tid  = threadIdx.x;
    const int lane = tid & 63;
    const int w    = tid >> 6;
    const int wr   = w >> 1;            // wave row (0/1) -> 64 rows
    const int wc   = w & 1;             // wave col (0/1) -> 64 cols
    const int n0   = blockIdx.x * 128;
    const int m0   = blockIdx.y * 128;

    // staging: idx0 = tid, idx1 = tid+256 ; kslot = idx>>7, row = idx&127
    const int r01 = tid & 127;
    const int ks0 = tid >> 7;
    const int ks1 = ks0 + 2;
    const _Float16* a0 = A  + (size_t)(m0 + r01) * lda + ks0 * 8;
    const _Float16* a1 = A  + (size_t)(m0 + r01) * lda + ks1 * 8;
    const _Float16* b0 = BT + (size_t)(n0 + r01) * K   + ks0 * 8;
    const _Float16* b1 = BT + (size_t)(n0 + r01) * K   + ks1 * 8;
    _Float16* sA0 = &As[0][0][0] + (size_t)tid * 8;
    _Float16* sA1 = sA0 + 2048;
    _Float16* sB0 = &Bs[0][0][0] + (size_t)tid * 8;
    _Float16* sB1 = sB0 + 2048;

    const int frow = lane & 15;
    const int fks  = lane >> 4;
    const _Float16* fA = &As[fks][wr * 64 + frow][0];
    const _Float16* fB = &Bs[fks][wc * 64 + frow][0];

    f32x4 acc[4][4] = {};

    for (int k0 = 0; k0 < K; k0 += 32) {
        __builtin_amdgcn_global_load_lds(GLOBAL_PTR(a0 + k0), LDS_PTR(sA0), 16, 0, 0);
        __builtin_amdgcn_global_load_lds(GLOBAL_PTR(a1 + k0), LDS_PTR(sA1), 16, 0, 0);
        __builtin_amdgcn_global_load_lds(GLOBAL_PTR(b0 + k0), LDS_PTR(sB0), 16, 0, 0);
        __builtin_amdgcn_global_load_lds(GLOBAL_PTR(b1 + k0), LDS_PTR(sB1), 16, 0, 0);
        __syncthreads();                      // drains vmcnt, LDS tile ready
        f16x8 af[4], bf[4];
        #pragma unroll
        for (int m = 0; m < 4; ++m) af[m] = *(const f16x8*)(fA + m * 16 * 8);
        #pragma unroll
        for (int n = 0; n < 4; ++n) bf[n] = *(const f16x8*)(fB + n * 16 * 8);
        #pragma unroll
        for (int m = 0; m < 4; ++m)
            #pragma unroll
            for (int n = 0; n < 4; ++n)
                acc[m][n] = __builtin_amdgcn_mfma_f32_16x16x32_f16(af[m], bf[n], acc[m][n], 0, 0, 0);
        __syncthreads();                      // readers done before next stage
    }

    // epilogue: D row = (lane>>4)*4 + r, col = lane&15 (verified C/D mapping)
    const int orow = (lane >> 4) * 2;         // *4 rows / ... (see below)
    #pragma unroll
    for (int m = 0; m < 4; ++m) {
        #pragma unroll
        for (int n = 0; n < 4; ++n) {
            const int gn = n0 + wc * 64 + n * 16 + (lane & 15);
            #pragma unroll
            for (int r = 0; r < 4; ++r) {
                const int gm = m0 + wr * 64 + m * 16 + (lane >> 4) * 4 + r;
                if (gm < M) {
                    float v = acc[m][n][r] + bias[gn];
                    v = silu_f(v);
                    if (GATED) v *= (float)gate[(size_t)((i0 + gm) >> 1) * H_N + gn];
                    C[(size_t)gm * N + gn] = (_Float16)v;
                }
            }
        }
    }
    (void)orow;
}

// ---------------------------------------------------------------------------
// Rotate: rot[ii, part*2432 + s*128 + c] = sum_b wigner[i0+ii, s, b] * x[node, b, c]
// fp32 math, fp16 output. One block per EY row, 256 threads.
// ---------------------------------------------------------------------------
__launch_bounds__(256)
__global__ void rotate_kernel(const float* __restrict__ x, const float* __restrict__ wigner,
                              const int* __restrict__ eidx, _Float16* __restrict__ rot, int i0)
{
    __shared__ float wig[SBR_N * SB_N];     // 931 floats
    __shared__ float xs[SB_N * C_N];        // 6272 floats
    const int ii = blockIdx.x;
    const int i = i0 + ii;
    const int e = i >> 1;
    const int tid = threadIdx.x;
    const int c = tid & 127;
    const int sg = tid >> 7;               // 0/1 : s-group

    for (int t = tid; t < SBR_N * SB_N; t += 256)
        wig[t] = wigner[(size_t)i * (SBR_N * SB_N) + t];

    for (int part = 0; part < 2; ++part) {
        const int node = eidx[part * E_N + e];
        __syncthreads();  // previous part's compute done (also covers wig load)
        for (int t = tid; t < (SB_N * C_N) / 4; t += 256)
            *(float4*)&xs[t * 4] = *(const float4*)(x + (size_t)node * (SB_N * C_N) + t * 4);
        __syncthreads();
        for (int s = sg; s < SBR_N; s += 2) {
            float acc = 0.f;
            #pragma unroll 7
            for (int b = 0; b < SB_N; ++b)
                acc += wig[s * SB_N + b] * xs[b * C_N + c];
            rot[(size_t)ii * KPROJ + part * NOUT + s * C_N + c] = (_Float16)acc;
        }
    }
}

// ---------------------------------------------------------------------------
// Combine: out[e,b,c] = sum_s wigner_inv[e,b,s] * 0.5*(h3[2eb,s,c] + h3[2eb+1,s,c])
// h3 is fp16; math/output fp32. One block per edge, 128 threads.
// ---------------------------------------------------------------------------
__launch_bounds__(128)
__global__ void combine_kernel(const _Float16* __restrict__ h3, const float* __restrict__ wigner_inv,
                               float* __restrict__ out, int e0)
{
    __shared__ float ms[SBR_N * C_N];       // 2432 floats
    __shared__ float wv[SB_N * SBR_N];      // 931 floats
    const int eb = blockIdx.x;
    const int e = e0 + eb;
    const int c = threadIdx.x;              // 0..127

    #pragma unroll
    for (int s = 0; s < SBR_N; ++s) {
        const float a = (float)h3[(size_t)(2 * eb) * NOUT + s * C_N + c];
        const float b = (float)h3[(size_t)(2 * eb + 1) * NOUT + s * C_N + c];
        ms[s * C_N + c] = 0.5f * (a + b);
    }
    for (int t = c; t < SB_N * SBR_N; t += 128)
        wv[t] = wigner_inv[(size_t)e * (SB_N * SBR_N) + t];
    __syncthreads();

    for (int b = 0; b < SB_N; ++b) {
        float acc = 0.f;
        #pragma unroll
        for (int s = 0; s < SBR_N; ++s)
            acc += wv[b * SBR_N + s] * ms[s * C_N + c];
        out[(size_t)e * (SB_N * C_N) + b * C_N + c] = acc;
    }
}

// ---------------------------------------------------------------------------
extern "C" void kernel_launch(void* const* d_in, const int* in_sizes, int n_in,
                              void* d_out, int out_size, void* d_ws, size_t ws_size,
                              hipStream_t stream)
{
    const float* x          = (const float*)d_in[0];
    const float* x_edge     = (const float*)d_in[1];
    const int*   eidx       = (const int*)d_in[2];
    const float* wigner     = (const float*)d_in[3];
    const float* wigner_inv = (const float*)d_in[4];
    const float* w_dist     = (const float*)d_in[5];
    const float* b_dist     = (const float*)d_in[6];
    const float* w_proj     = (const float*)d_in[7];
    const float* b_proj     = (const float*)d_in[8];
    const float* w_edge     = (const float*)d_in[9];
    const float* b_edge     = (const float*)d_in[10];
    const float* w_out      = (const float*)d_in[11];
    const float* b_out      = (const float*)d_in[12];
    float* out = (float*)d_out;

    // ---- workspace layout (all fp16 buffers, 256B aligned) ----
    char* wsp = (char*)d_ws;
    auto alloc = [&](size_t bytes) -> char* {
        char* p = wsp;
        wsp += (bytes + 255) & ~(size_t)255;
        return p;
    };
    const int XE_ROWS = 10112;                       // 79*128, padded for staging reads
    _Float16* gate = (_Float16*)alloc((size_t)E_N * H_N * sizeof(_Float16));
    _Float16* wTd  = (_Float16*)alloc((size_t)H_N * NBF_N * sizeof(_Float16));     // [256][512]
    _Float16* wTp  = (_Float16*)alloc((size_t)H_N * KPROJ * sizeof(_Float16));     // [256][4864]
    _Float16* wTe  = (_Float16*)alloc((size_t)H_N * H_N * sizeof(_Float16));       // [256][256]
    _Float16* wTo  = (_Float16*)alloc((size_t)NOUT * H_N * sizeof(_Float16));      // [2432][256]
    _Float16* xeh  = (_Float16*)alloc((size_t)XE_ROWS * NBF_N * sizeof(_Float16));

    const size_t used = (size_t)(wsp - (char*)d_ws);
    const size_t avail = ws_size > used ? ws_size - used : 0;
    const size_t per_row = (size_t)(KPROJ + H_N + H_N) * sizeof(_Float16);   // 10752 B
    long cimax = (long)(avail / per_row) & ~127L;    // multiple of 128 (even)
    if (cimax > 20096) cimax = 20096;                // ceil(2E/128)*128
    if (cimax < 128) cimax = 128;                    // last-resort (assumes ws adequate)

    _Float16* rot = (_Float16*)alloc((size_t)cimax * KPROJ * sizeof(_Float16)); // reused as h3
    _Float16* h1  = (_Float16*)alloc((size_t)cimax * H_N * sizeof(_Float16));
    _Float16* h2  = (_Float16*)alloc((size_t)cimax * H_N * sizeof(_Float16));

    // ---- one-time prep: weight transposes + x_edge convert ----
    transpose_to_f16<<<dim3(NBF_N / 32, H_N / 32), 256, 0, stream>>>(w_dist, wTd, NBF_N, H_N);
    transpose_to_f16<<<dim3(KPROJ / 32, H_N / 32), 256, 0, stream>>>(w_proj, wTp, KPROJ, H_N);
    transpose_to_f16<<<dim3(H_N / 32, H_N / 32), 256, 0, stream>>>(w_edge, wTe, H_N, H_N);
    transpose_to_f16<<<dim3(H_N / 32, NOUT / 32), 256, 0, stream>>>(w_out, wTo, H_N, NOUT);
    cvt_to_f16<<<dim3(1024), 256, 0, stream>>>(x_edge, xeh, (E_N * NBF_N) / 4);

    // 1. gate[e,h] = silu(x_edge @ w_dist + b_dist), fp16 out
    gemm_f16<0><<<dim3(H_N / 128, XE_ROWS / 128), 256, 0, stream>>>(
        xeh, NBF_N, wTd, b_dist, nullptr, gate, E_N, H_N, NBF_N, 0);

    for (long i0 = 0; i0 < 2L * E_N; i0 += cimax) {
        long ci = 2L * E_N - i0;
        if (ci > cimax) ci = cimax;
        const unsigned cb = (unsigned)((ci + 127) / 128);

        // 2. rotate source+target into rot[ci, 4864] (fp16)
        rotate_kernel<<<dim3((unsigned)ci), 256, 0, stream>>>(x, wigner, eidx, rot, (int)i0);

        // 3. h1 = silu(rot @ w_proj + b_proj) * gate[e]
        gemm_f16<1><<<dim3(H_N / 128, cb), 256, 0, stream>>>(
            rot, KPROJ, wTp, b_proj, gate, h1, (int)ci, H_N, KPROJ, (int)i0);

        // 4. h2 = silu(h1 @ w_edge + b_edge)
        gemm_f16<0><<<dim3(H_N / 128, cb), 256, 0, stream>>>(
            h1, H_N, wTe, b_edge, nullptr, h2, (int)ci, H_N, H_N, 0);

        // 5. h3 = silu(h2 @ w_out + b_out)   (reuses rot buffer)
        gemm_f16<0><<<dim3(NOUT / 128, cb), 256, 0, stream>>>(
            h2, H_N, wTo, b_out, nullptr, rot, (int)ci, NOUT, H_N, 0);

        // 6. out[e] = wigner_inv[e] @ mean_Y(h3)
        combine_kernel<<<dim3((unsigned)(ci / 2)), 128, 0, stream>>>(
            rot, wigner_inv, out, (int)(i0 / 2));
    }
}

// Round 2
// 1036.894 us; speedup vs baseline: 2.0370x; 1.2945x over previous
//
#include <hip/hip_runtime.h>

#define E_N   10000
#define SB_N  49
#define SBR_N 19
#define C_N   128
#define H_N   256
#define NBF_N 512
#define KPROJ 4864   // 2*SBR*C
#define NOUT  2432   // SBR*C
#define BPAD  56     // b-dim (49) padded to 56 fp16 (112 B, 16B-aligned rows)

typedef _Float16 f16x8 __attribute__((ext_vector_type(8)));
typedef _Float16 f16x4 __attribute__((ext_vector_type(4)));
typedef _Float16 f16x2 __attribute__((ext_vector_type(2)));
typedef float    f32x4 __attribute__((ext_vector_type(4)));

__device__ __forceinline__ float silu_f(float v) { return v / (1.0f + __expf(-v)); }

__device__ __forceinline__ float dot2f(f16x2 a, f16x2 b, float c) {
#if defined(__has_builtin)
#if __has_builtin(__builtin_amdgcn_fdot2)
    return __builtin_amdgcn_fdot2(a, b, c, false);
#else
    return c + (float)a[0] * (float)b[0] + (float)a[1] * (float)b[1];
#endif
#else
    return c + (float)a[0] * (float)b[0] + (float)a[1] * (float)b[1];
#endif
}

#define GLOBAL_PTR(p) ((const __attribute__((address_space(1))) void*)(p))
#define LDS_PTR(p)    ((__attribute__((address_space(3))) void*)(p))

// ---------------------------------------------------------------------------
// Tiled transpose + fp32->fp16: out[n*K + k] = (f16) in[k*N + n]
// grid: (ceil(K/32), ceil(N/32)), 256 threads (32x8)
// ---------------------------------------------------------------------------
__launch_bounds__(256)
__global__ void transpose_to_f16(const float* __restrict__ in, _Float16* __restrict__ out,
                                 int K, int N)
{
    __shared__ float tile[32][33];
    const int k0 = blockIdx.x * 32;
    const int n0 = blockIdx.y * 32;
    const int tx = threadIdx.x & 31;
    const int ty = threadIdx.x >> 5;           // 0..7
    #pragma unroll
    for (int i = ty; i < 32; i += 8)
        if (k0 + i < K && n0 + tx < N)
            tile[i][tx] = in[(size_t)(k0 + i) * N + (n0 + tx)];
    __syncthreads();
    #pragma unroll
    for (int i = ty; i < 32; i += 8)
        if (n0 + i < N && k0 + tx < K)
            out[(size_t)(n0 + i) * K + (k0 + tx)] = (_Float16)tile[tx][i];
}

// ---------------------------------------------------------------------------
// fp32 -> fp16 bulk convert (float4 -> 4x f16), n4 = n/4
// ---------------------------------------------------------------------------
__launch_bounds__(256)
__global__ void cvt_to_f16(const float* __restrict__ in, _Float16* __restrict__ out, int n4)
{
    int i = blockIdx.x * blockDim.x + threadIdx.x;
    const int stride = gridDim.x * blockDim.x;
    for (; i < n4; i += stride) {
        const float4 v = ((const float4*)in)[i];
        f16x4 o; o[0] = (_Float16)v.x; o[1] = (_Float16)v.y; o[2] = (_Float16)v.z; o[3] = (_Float16)v.w;
        ((f16x4*)out)[i] = o;
    }
}

// ---------------------------------------------------------------------------
// Prep: xt[n][c][b] = (f16) x[n][b][c], b padded to BPAD=56 with zeros.
// Column of x becomes a contiguous 112 B fp16 run -> dot2-pair friendly.
// One block per node, 256 threads.
// ---------------------------------------------------------------------------
__launch_bounds__(256)
__global__ void prep_xt(const float* __restrict__ x, _Float16* __restrict__ xt)
{
    __shared__ float xs[SB_N * C_N];           // 6272 f32
    __shared__ _Float16 xl[C_N * BPAD];        // 7168 f16
    const int n = blockIdx.x;
    const int tid = threadIdx.x;
    for (int t = tid; t < (SB_N * C_N) / 4; t += 256)
        ((float4*)xs)[t] = ((const float4*)(x + (size_t)n * (SB_N * C_N)))[t];
    __syncthreads();
    for (int t = tid; t < C_N * (BPAD / 2); t += 256) {   // 3584 pair-slots
        const int c = t & 127;
        const int j = t >> 7;                   // 0..27
        const int b0 = 2 * j, b1 = 2 * j + 1;
        f16x2 p;
        p[0] = (b0 < SB_N) ? (_Float16)xs[b0 * C_N + c] : (_Float16)0.f;
        p[1] = (b1 < SB_N) ? (_Float16)xs[b1 * C_N + c] : (_Float16)0.f;
        ((f16x2*)xl)[c * (BPAD / 2) + j] = p;
    }
    __syncthreads();
    _Float16* dst = xt + (size_t)n * (C_N * BPAD);
    for (int t = tid; t < (C_N * BPAD) / 4; t += 256)     // 1792 x 8B
        ((f16x4*)dst)[t] = ((const f16x4*)xl)[t];
}

// ---------------------------------------------------------------------------
// MFMA GEMM: C[M,N](f16) = silu(A[M,K](f16) @ BT[N,K](f16)^T + bias[N]) [* gate]
// BM=BN=128, BK=32, 256 threads = 4 waves (2x2), 4x4 16x16x32 frags per wave.
// ---------------------------------------------------------------------------
template<int GATED>
__launch_bounds__(256, 2)
__global__ void gemm_f16(const _Float16* __restrict__ A, int lda,
                         const _Float16* __restrict__ BT,
                         const float* __restrict__ bias,
                         const _Float16* __restrict__ gate,
                         _Float16* __restrict__ C,
                         int M, int N, int K, int i0)
{
    __shared__ __align__(16) _Float16 As[4][128][8];
    __shared__ __align__(16) _Float16 Bs[4][128][8];
    const int tid  = threadIdx.x;
    const int lane = tid & 63;
    const int w    = tid >> 6;
    const int wr   = w >> 1;
    const int wc   = w & 1;
    const int n0   = blockIdx.x * 128;
    const int m0   = blockIdx.y * 128;

    const int r01 = tid & 127;
    const int ks0 = tid >> 7;
    const int ks1 = ks0 + 2;
    const _Float16* a0 = A  + (size_t)(m0 + r01) * lda + ks0 * 8;
    const _Float16* a1 = A  + (size_t)(m0 + r01) * lda + ks1 * 8;
    const _Float16* b0 = BT + (size_t)(n0 + r01) * K   + ks0 * 8;
    const _Float16* b1 = BT + (size_t)(n0 + r01) * K   + ks1 * 8;
    _Float16* sA0 = &As[0][0][0] + (size_t)tid * 8;
    _Float16* sA1 = sA0 + 2048;
    _Float16* sB0 = &Bs[0][0][0] + (size_t)tid * 8;
    _Float16* sB1 = sB0 + 2048;

    const int frow = lane & 15;
    const int fks  = lane >> 4;
    const _Float16* fA = &As[fks][wr * 64 + frow][0];
    const _Float16* fB = &Bs[fks][wc * 64 + frow][0];

    f32x4 acc[4][4] = {};

    for (int k0 = 0; k0 < K; k0 += 32) {
        __builtin_amdgcn_global_load_lds(GLOBAL_PTR(a0 + k0), LDS_PTR(sA0), 16, 0, 0);
        __builtin_amdgcn_global_load_lds(GLOBAL_PTR(a1 + k0), LDS_PTR(sA1), 16, 0, 0);
        __builtin_amdgcn_global_load_lds(GLOBAL_PTR(b0 + k0), LDS_PTR(sB0), 16, 0, 0);
        __builtin_amdgcn_global_load_lds(GLOBAL_PTR(b1 + k0), LDS_PTR(sB1), 16, 0, 0);
        __syncthreads();
        f16x8 af[4], bf[4];
        #pragma unroll
        for (int m = 0; m < 4; ++m) af[m] = *(const f16x8*)(fA + m * 16 * 8);
        #pragma unroll
        for (int n = 0; n < 4; ++n) bf[n] = *(const f16x8*)(fB + n * 16 * 8);
        #pragma unroll
        for (int m = 0; m < 4; ++m)
            #pragma unroll
            for (int n = 0; n < 4; ++n)
                acc[m][n] = __builtin_amdgcn_mfma_f32_16x16x32_f16(af[m], bf[n], acc[m][n], 0, 0, 0);
        __syncthreads();
    }

    #pragma unroll
    for (int m = 0; m < 4; ++m) {
        #pragma unroll
        for (int n = 0; n < 4; ++n) {
            const int gn = n0 + wc * 64 + n * 16 + (lane & 15);
            #pragma unroll
            for (int r = 0; r < 4; ++r) {
                const int gm = m0 + wr * 64 + m * 16 + (lane >> 4) * 4 + r;
                if (gm < M) {
                    float v = acc[m][n][r] + bias[gn];
                    v = silu_f(v);
                    if (GATED) v *= (float)gate[(size_t)((i0 + gm) >> 1) * H_N + gn];
                    C[(size_t)gm * N + gn] = (_Float16)v;
                }
            }
        }
    }
}

// ---------------------------------------------------------------------------
// Rotate v2: one block per EDGE (both y, both parts).
// rot[2(e-e0)+y, part*2432 + s*128 + c] = sum_b wig[2e+y,s,b] * x[node_part,b,c]
// x pre-transposed fp16 (xt), wigner converted f32->f16 in-stage.
// Inner loop: register-cached x column (28 f16x2) x v_dot2 with f32 accum.
// ---------------------------------------------------------------------------
__launch_bounds__(256)
__global__ void rotate_v2(const _Float16* __restrict__ xt, const float* __restrict__ wigner,
                          const int* __restrict__ eidx, _Float16* __restrict__ rot, int e0)
{
    __shared__ __align__(16) _Float16 xs_t[2][C_N * BPAD];   // 2 x 14336 B
    __shared__ __align__(16) _Float16 wg[2][SBR_N * BPAD];   // 2 x 2128 B
    const int tid = threadIdx.x;
    const int e = e0 + blockIdx.x;
    const int node0 = eidx[0 * E_N + e];
    const int node1 = eidx[1 * E_N + e];

    const f16x8* s0 = (const f16x8*)(xt + (size_t)node0 * (C_N * BPAD));
    const f16x8* s1 = (const f16x8*)(xt + (size_t)node1 * (C_N * BPAD));
    for (int t = tid; t < (C_N * BPAD) / 8; t += 256) {      // 896
        *(f16x8*)&xs_t[0][t * 8] = s0[t];
        *(f16x8*)&xs_t[1][t * 8] = s1[t];
    }
    // wigner rows 2e, 2e+1: f32 -> f16, laid out [y][s*BPAD + b], pads zeroed
    for (int t = tid; t < 2 * SBR_N * SB_N; t += 256) {      // 1862
        const int y = t / (SBR_N * SB_N);
        const int sb = t - y * (SBR_N * SB_N);
        const int s = sb / SB_N, b = sb - s * SB_N;
        wg[y][s * BPAD + b] = (_Float16)wigner[((size_t)(2 * e) + y) * (SBR_N * SB_N) + sb];
    }
    for (int t = tid; t < 2 * SBR_N * (BPAD - SB_N); t += 256) {  // 266 pad zeros
        const int y = t / (SBR_N * (BPAD - SB_N));
        const int r = t - y * (SBR_N * (BPAD - SB_N));
        const int s = r / (BPAD - SB_N), j = r - s * (BPAD - SB_N);
        wg[y][s * BPAD + SB_N + j] = (_Float16)0.f;
    }
    __syncthreads();

    const int c = tid & 127;
    const int part = tid >> 7;

    f16x2 xc[BPAD / 2];
    const f16x2* xr = (const f16x2*)&xs_t[part][c * BPAD];
    #pragma unroll
    for (int j = 0; j < BPAD / 2; ++j) xc[j] = xr[j];

    const size_t rowbase = 2 * (size_t)blockIdx.x;
    #pragma unroll
    for (int y = 0; y < 2; ++y) {
        _Float16* orow = rot + (rowbase + y) * KPROJ + part * NOUT + c;
        for (int s = 0; s < SBR_N; ++s) {
            const f16x2* wr = (const f16x2*)&wg[y][s * BPAD];
            float acc = 0.f;
            #pragma unroll
            for (int j = 0; j < BPAD / 2; ++j)
                acc = dot2f(xc[j], wr[j], acc);
            orow[s * C_N] = (_Float16)acc;
        }
    }
}

// ---------------------------------------------------------------------------
// Combine: out[e,b,c] = sum_s wigner_inv[e,b,s] * 0.5*(h3[2eb,s,c] + h3[2eb+1,s,c])
// ---------------------------------------------------------------------------
__launch_bounds__(128)
__global__ void combine_kernel(const _Float16* __restrict__ h3, const float* __restrict__ wigner_inv,
                               float* __restrict__ out, int e0)
{
    __shared__ float ms[SBR_N * C_N];
    __shared__ float wv[SB_N * SBR_N];
    const int eb = blockIdx.x;
    const int e = e0 + eb;
    const int c = threadIdx.x;

    #pragma unroll
    for (int s = 0; s < SBR_N; ++s) {
        const float a = (float)h3[(size_t)(2 * eb) * NOUT + s * C_N + c];
        const float b = (float)h3[(size_t)(2 * eb + 1) * NOUT + s * C_N + c];
        ms[s * C_N + c] = 0.5f * (a + b);
    }
    for (int t = c; t < SB_N * SBR_N; t += 128)
        wv[t] = wigner_inv[(size_t)e * (SB_N * SBR_N) + t];
    __syncthreads();

    for (int b = 0; b < SB_N; ++b) {
        float acc = 0.f;
        #pragma unroll
        for (int s = 0; s < SBR_N; ++s)
            acc += wv[b * SBR_N + s] * ms[s * C_N + c];
        out[(size_t)e * (SB_N * C_N) + b * C_N + c] = acc;
    }
}

// ---------------------------------------------------------------------------
extern "C" void kernel_launch(void* const* d_in, const int* in_sizes, int n_in,
                              void* d_out, int out_size, void* d_ws, size_t ws_size,
                              hipStream_t stream)
{
    const float* x          = (const float*)d_in[0];
    const float* x_edge     = (const float*)d_in[1];
    const int*   eidx       = (const int*)d_in[2];
    const float* wigner     = (const float*)d_in[3];
    const float* wigner_inv = (const float*)d_in[4];
    const float* w_dist     = (const float*)d_in[5];
    const float* b_dist     = (const float*)d_in[6];
    const float* w_proj     = (const float*)d_in[7];
    const float* b_proj     = (const float*)d_in[8];
    const float* w_edge     = (const float*)d_in[9];
    const float* b_edge     = (const float*)d_in[10];
    const float* w_out      = (const float*)d_in[11];
    const float* b_out      = (const float*)d_in[12];
    float* out = (float*)d_out;

    // ---- workspace layout ----
    char* wsp = (char*)d_ws;
    auto alloc = [&](size_t bytes) -> char* {
        char* p = wsp;
        wsp += (bytes + 255) & ~(size_t)255;
        return p;
    };
    const int XE_ROWS = 10112;                       // 79*128, padded for staging reads
    _Float16* gate = (_Float16*)alloc((size_t)E_N * H_N * sizeof(_Float16));
    _Float16* wTd  = (_Float16*)alloc((size_t)H_N * NBF_N * sizeof(_Float16));
    _Float16* wTp  = (_Float16*)alloc((size_t)H_N * KPROJ * sizeof(_Float16));
    _Float16* wTe  = (_Float16*)alloc((size_t)H_N * H_N * sizeof(_Float16));
    _Float16* wTo  = (_Float16*)alloc((size_t)NOUT * H_N * sizeof(_Float16));
    _Float16* xeh  = (_Float16*)alloc((size_t)XE_ROWS * NBF_N * sizeof(_Float16));
    _Float16* xt   = (_Float16*)alloc((size_t)5000 * C_N * BPAD * sizeof(_Float16)); // 71.7 MB

    const size_t used = (size_t)(wsp - (char*)d_ws);
    const size_t avail = ws_size > used ? ws_size - used : 0;
    const size_t per_row = (size_t)(KPROJ + H_N + H_N) * sizeof(_Float16);   // 10752 B
    long cimax = (long)(avail / per_row) & ~127L;    // multiple of 128 (even)
    if (cimax > 20096) cimax = 20096;
    if (cimax < 128) cimax = 128;

    _Float16* rot = (_Float16*)alloc((size_t)cimax * KPROJ * sizeof(_Float16)); // reused as h3
    _Float16* h1  = (_Float16*)alloc((size_t)cimax * H_N * sizeof(_Float16));
    _Float16* h2  = (_Float16*)alloc((size_t)cimax * H_N * sizeof(_Float16));

    // ---- one-time prep ----
    transpose_to_f16<<<dim3(NBF_N / 32, H_N / 32), 256, 0, stream>>>(w_dist, wTd, NBF_N, H_N);
    transpose_to_f16<<<dim3(KPROJ / 32, H_N / 32), 256, 0, stream>>>(w_proj, wTp, KPROJ, H_N);
    transpose_to_f16<<<dim3(H_N / 32, H_N / 32), 256, 0, stream>>>(w_edge, wTe, H_N, H_N);
    transpose_to_f16<<<dim3(H_N / 32, NOUT / 32), 256, 0, stream>>>(w_out, wTo, H_N, NOUT);
    cvt_to_f16<<<dim3(1024), 256, 0, stream>>>(x_edge, xeh, (E_N * NBF_N) / 4);
    prep_xt<<<dim3(5000), 256, 0, stream>>>(x, xt);

    // 1. gate[e,h] = silu(x_edge @ w_dist + b_dist), fp16 out
    gemm_f16<0><<<dim3(H_N / 128, XE_ROWS / 128), 256, 0, stream>>>(
        xeh, NBF_N, wTd, b_dist, nullptr, gate, E_N, H_N, NBF_N, 0);

    for (long i0 = 0; i0 < 2L * E_N; i0 += cimax) {
        long ci = 2L * E_N - i0;
        if (ci > cimax) ci = cimax;
        const unsigned cb = (unsigned)((ci + 127) / 128);

        // 2. rotate source+target into rot[ci, 4864] (fp16), one block per edge
        rotate_v2<<<dim3((unsigned)(ci / 2)), 256, 0, stream>>>(
            xt, wigner, eidx, rot, (int)(i0 / 2));

        // 3. h1 = silu(rot @ w_proj + b_proj) * gate[e]
        gemm_f16<1><<<dim3(H_N / 128, cb), 256, 0, stream>>>(
            rot, KPROJ, wTp, b_proj, gate, h1, (int)ci, H_N, KPROJ, (int)i0);

        // 4. h2 = silu(h1 @ w_edge + b_edge)
        gemm_f16<0><<<dim3(H_N / 128, cb), 256, 0, stream>>>(
            h1, H_N, wTe, b_edge, nullptr, h2, (int)ci, H_N, H_N, 0);

        // 5. h3 = silu(h2 @ w_out + b_out)   (reuses rot buffer)
        gemm_f16<0><<<dim3(NOUT / 128, cb), 256, 0, stream>>>(
            h2, H_N, wTo, b_out, nullptr, rot, (int)ci, NOUT, H_N, 0);

        // 6. out[e] = wigner_inv[e] @ mean_Y(h3)
        combine_kernel<<<dim3((unsigned)(ci / 2)), 128, 0, stream>>>(
            rot, wigner_inv, out, (int)(i0 / 2));
    }
}